// Round 1
// baseline (406.042 us; speedup 1.0000x reference)
//
#include <hip/hip_runtime.h>
#include <stdint.h>

typedef unsigned short u16;
typedef float v4f __attribute__((ext_vector_type(4)));
typedef short v8s __attribute__((ext_vector_type(8)));

#define B_   8192
#define IN_  1024
#define OUT_ 1024
#define D_   8

#define BM 128
#define BN 128
#define BK 32

__device__ __forceinline__ u16 f2bf(float f) {
  uint32_t u = __float_as_uint(f);
  u += 0x7fffu + ((u >> 16) & 1u);   // round-to-nearest-even (inputs are finite)
  return (u16)(u >> 16);
}

// Convert input (8M fp32) and weights (8M fp32) to bf16 in workspace.
__global__ __launch_bounds__(256) void convert_kernel(
    const float* __restrict__ input, const float* __restrict__ weights,
    u16* __restrict__ inBf, u16* __restrict__ wtBf) {
  int i4 = blockIdx.x * blockDim.x + threadIdx.x;   // one float4 per thread
  const int n4 = (B_ * IN_) / 4;
  const float* src;
  u16* dst;
  int idx;
  if (i4 < n4) { src = input;   dst = inBf; idx = i4; }
  else         { src = weights; dst = wtBf; idx = i4 - n4; }
  float4 v = ((const float4*)src)[idx];
  ushort4 o;
  o.x = f2bf(v.x); o.y = f2bf(v.y); o.z = f2bf(v.z); o.w = f2bf(v.w);
  ((ushort4*)dst)[idx] = o;
}

__device__ __forceinline__ void gload_lds16(const u16* g, u16* l) {
  typedef __attribute__((address_space(1))) void gvoid;
  typedef __attribute__((address_space(3))) void lvoid;
  __builtin_amdgcn_global_load_lds((gvoid*)g, (lvoid*)l, 16, 0, 0);
}

// GEMM: out[b,o] = sum_d w[b,d] * sum_i inBf[b,i]*wtBf[d,o,i] + sum_d w[b,d]*biases[d,o]
// m97 structure: 128x128 tile, BK=32, 4 waves each computing a 64x64 quadrant via
// 4x4 tiles of mfma_f32_16x16x32_bf16. Per-d-epoch accumulator folded by w[b,d].
__global__ __launch_bounds__(256) void gemm_dyn(
    const u16* __restrict__ A,        // [B_][IN_] bf16 (unscaled input)
    const u16* __restrict__ Wt,       // [D_][OUT_][IN_] bf16
    const float* __restrict__ w,      // [B_][D_]
    const float* __restrict__ biases, // [D_][OUT_]
    float* __restrict__ out) {        // [B_][OUT_]
  __shared__ __align__(16) u16 As[BM * BK];   // [m][k] row-major, 8 KB
  __shared__ __align__(16) u16 Bs[BN * BK];   // [n][k] row-major, 8 KB

  const int tid  = threadIdx.x;
  const int wid  = tid >> 6;
  const int lane = tid & 63;
  const int wr   = wid >> 1, wc = wid & 1;    // wave quadrant in 128x128
  const int quad = lane >> 4, l16 = lane & 15;
  const int m0   = blockIdx.y * BM;
  const int n0   = blockIdx.x * BN;

  // ---- staging: 512 chunks of 16B per 8KB tile; 2 chunks/thread, wave-contiguous
  const int c0  = wid * 128 + lane;
  const int c1  = c0 + 64;
  const int rA0 = c0 >> 2, cA0 = (c0 & 3) << 3;
  const int rA1 = c1 >> 2, cA1 = (c1 & 3) << 3;
  const u16* aP0 = A + (size_t)(m0 + rA0) * IN_ + cA0;
  const u16* aP1 = A + (size_t)(m0 + rA1) * IN_ + cA1;
  const u16* bB0 = Wt + (size_t)(n0 + rA0) * IN_ + cA0;
  const u16* bB1 = Wt + (size_t)(n0 + rA1) * IN_ + cA1;
  u16* lA0 = As + c0 * 8;
  u16* lA1 = As + c1 * 8;
  u16* lB0 = Bs + c0 * 8;
  u16* lB1 = Bs + c1 * 8;

  // ---- fragment LDS offsets (u16 index); mt/nt adds 16*BK
  const int aOff = (wr * 64 + l16) * BK + quad * 8;
  const int bOff = (wc * 64 + l16) * BK + quad * 8;

  const v4f vzero = {0.f, 0.f, 0.f, 0.f};
  v4f fin[4][4];
#pragma unroll
  for (int mt = 0; mt < 4; ++mt)
#pragma unroll
    for (int nt = 0; nt < 4; ++nt) fin[mt][nt] = vzero;

  for (int d = 0; d < D_; ++d) {
    const u16* bP0 = bB0 + (size_t)d * OUT_ * IN_;
    const u16* bP1 = bB1 + (size_t)d * OUT_ * IN_;
    v4f acc[4][4];
#pragma unroll
    for (int mt = 0; mt < 4; ++mt)
#pragma unroll
      for (int nt = 0; nt < 4; ++nt) acc[mt][nt] = vzero;

    for (int it = 0; it < 32; ++it) {
      const int i0 = it * BK;
      gload_lds16(aP0 + i0, lA0);
      gload_lds16(aP1 + i0, lA1);
      gload_lds16(bP0 + i0, lB0);
      gload_lds16(bP1 + i0, lB1);
      __builtin_amdgcn_s_waitcnt(0);
      __syncthreads();

      v8s af[4], bf[4];
#pragma unroll
      for (int mt = 0; mt < 4; ++mt)
        af[mt] = *(const v8s*)(As + aOff + mt * 16 * BK);
#pragma unroll
      for (int nt = 0; nt < 4; ++nt)
        bf[nt] = *(const v8s*)(Bs + bOff + nt * 16 * BK);
#pragma unroll
      for (int mt = 0; mt < 4; ++mt)
#pragma unroll
        for (int nt = 0; nt < 4; ++nt)
          acc[mt][nt] = __builtin_amdgcn_mfma_f32_16x16x32_bf16(
              af[mt], bf[nt], acc[mt][nt], 0, 0, 0);
      __syncthreads();
    }

    // fold this d-epoch into fin with per-row scale w[row, d]
#pragma unroll
    for (int mt = 0; mt < 4; ++mt) {
      const int rowb = m0 + wr * 64 + mt * 16 + quad * 4;
#pragma unroll
      for (int r = 0; r < 4; ++r) {
        const float ws_ = w[(size_t)(rowb + r) * D_ + d];
#pragma unroll
        for (int nt = 0; nt < 4; ++nt) fin[mt][nt][r] += ws_ * acc[mt][nt][r];
      }
    }
  }

  // ---- epilogue: add bias term sum_d w[b,d]*biases[d,o], store fp32
  float bcol[4][8];
#pragma unroll
  for (int nt = 0; nt < 4; ++nt) {
    const int col = n0 + wc * 64 + nt * 16 + l16;
#pragma unroll
    for (int dd = 0; dd < 8; ++dd) bcol[nt][dd] = biases[dd * OUT_ + col];
  }
#pragma unroll
  for (int mt = 0; mt < 4; ++mt) {
#pragma unroll
    for (int r = 0; r < 4; ++r) {
      const int grow = m0 + wr * 64 + mt * 16 + quad * 4 + r;
      const v4f* wp = (const v4f*)(w + (size_t)grow * D_);
      const v4f wa = wp[0], wb = wp[1];
#pragma unroll
      for (int nt = 0; nt < 4; ++nt) {
        const int col = n0 + wc * 64 + nt * 16 + l16;
        const float bias = wa[0] * bcol[nt][0] + wa[1] * bcol[nt][1] +
                           wa[2] * bcol[nt][2] + wa[3] * bcol[nt][3] +
                           wb[0] * bcol[nt][4] + wb[1] * bcol[nt][5] +
                           wb[2] * bcol[nt][6] + wb[3] * bcol[nt][7];
        out[(size_t)grow * OUT_ + col] = fin[mt][nt][r] + bias;
      }
    }
  }
}

extern "C" void kernel_launch(void* const* d_in, const int* in_sizes, int n_in,
                              void* d_out, int out_size, void* d_ws, size_t ws_size,
                              hipStream_t stream) {
  const float* input   = (const float*)d_in[0];
  const float* w       = (const float*)d_in[1];
  const float* weights = (const float*)d_in[2];
  const float* biases  = (const float*)d_in[3];
  float* out = (float*)d_out;

  u16* inBf = (u16*)d_ws;                       // 16 MB
  u16* wtBf = inBf + (size_t)B_ * IN_;          // 16 MB

  const int totalF4 = (B_ * IN_ + D_ * OUT_ * IN_) / 4;   // 4M
  convert_kernel<<<dim3(totalF4 / 256), 256, 0, stream>>>(input, weights, inBf, wtBf);
  gemm_dyn<<<dim3(OUT_ / BN, B_ / BM), 256, 0, stream>>>(inBf, wtBf, w, biases, out);
}